// Round 4
// baseline (10606.218 us; speedup 1.0000x reference)
//
#include <hip/hip_runtime.h>
#include <stdint.h>

#define SEQ  2048
#define HID  2048
#define INP  1024
#define OUTW 512

typedef _Float16 half2_t __attribute__((ext_vector_type(2)));
typedef unsigned long long ull_t;

#if __has_builtin(__builtin_amdgcn_fdot2)
#define FDOT2(a,b,c) __builtin_amdgcn_fdot2((a),(b),(c),false)
#else
__device__ __forceinline__ float FDOT2(half2_t a, half2_t b, float c){
  return c + (float)a[0]*(float)b[0] + (float)a[1]*(float)b[1];
}
#endif

__device__ __forceinline__ half2_t u2h(unsigned int u){ return __builtin_bit_cast(half2_t, u); }
__device__ __forceinline__ float sigmoid_f(float x){ return 1.0f/(1.0f + __expf(-x)); }
__device__ __forceinline__ float tanh_f(float x){
  x = fminf(15.0f, fmaxf(-15.0f, x));
  float e = __expf(-2.0f*x);
  return (1.0f - e)/(1.0f + e);
}
// any 16-bit half still equal to the 0xFFFF sentinel? (real f16 h, |h|<1, never is)
__device__ __forceinline__ bool bad16(ull_t q){
  return ((unsigned short)(q)      == 0xFFFFu) | ((unsigned short)(q>>16) == 0xFFFFu) |
         ((unsigned short)(q>>32)  == 0xFFFFu) | ((unsigned short)(q>>48) == 0xFFFFu);
}

// ---------------- Phase 0: sentinel-fill comm (f16) + zero zcomm row ----------------
__global__ __launch_bounds__(256)
void fill_comm(uint4* __restrict__ comm4, uint4* __restrict__ zc4){
  size_t i = (size_t)blockIdx.x*256 + threadIdx.x;   // 524,288 uint4 = 8 MB
  comm4[i] = make_uint4(~0u,~0u,~0u,~0u);
  if (i < 256) zc4[i] = make_uint4(0,0,0,0);         // 4 KB f16 zeros
}

// ---------------- Phase A: xp16[b][t][u*4+slot] = f16(W_g[j][2048:]@x_t + b_g[j]) ----------------
// slot order per unit: [f, cbar, i, o] to match the scan's reduce lane mapping.
__global__ __launch_bounds__(256)
void xproj_gemm(const float* __restrict__ Wf, const float* __restrict__ Wi,
                const float* __restrict__ Wc, const float* __restrict__ Wo,
                const float* __restrict__ bfv, const float* __restrict__ biv,
                const float* __restrict__ bcv, const float* __restrict__ bov,
                const float* __restrict__ X, unsigned short* __restrict__ xp16)
{
  __shared__ float As[16][68];
  __shared__ float Bs[16][68];
  const int t0 = blockIdx.x * 64;
  const int r0 = blockIdx.y * 64;
  const int gate = r0 >> 11;
  const int j0 = r0 & 2047;
  const float* Wg = gate==0?Wf:gate==1?Wi:gate==2?Wc:Wo;
  const float* bg = gate==0?bfv:gate==1?biv:gate==2?bcv:bov;
  const int slot = (gate==0)?0:(gate==1)?2:(gate==2)?1:3;
  const int tid = threadIdx.x;
  const int tx = tid & 15, ty = tid >> 4;
  const int lr = tid >> 2;
  const int lk = (tid & 3) * 4;
  float acc[4][4] = {};
  for (int k0 = 0; k0 < INP; k0 += 16){
    float4 av = *(const float4*)(Wg + (size_t)(j0+lr)*3072 + 2048 + k0 + lk);
    float4 bv = *(const float4*)(X  + (size_t)(t0+lr)*INP  + k0 + lk);
    __syncthreads();
    As[lk+0][lr]=av.x; As[lk+1][lr]=av.y; As[lk+2][lr]=av.z; As[lk+3][lr]=av.w;
    Bs[lk+0][lr]=bv.x; Bs[lk+1][lr]=bv.y; Bs[lk+2][lr]=bv.z; Bs[lk+3][lr]=bv.w;
    __syncthreads();
    #pragma unroll
    for (int kk=0;kk<16;kk++){
      float a[4], bb[4];
      #pragma unroll
      for (int i=0;i<4;i++) a[i]  = As[kk][ty*4+i];
      #pragma unroll
      for (int j=0;j<4;j++) bb[j] = Bs[kk][tx*4+j];
      #pragma unroll
      for (int i=0;i<4;i++)
        #pragma unroll
        for (int j=0;j<4;j++)
          acc[i][j] = fmaf(a[i], bb[j], acc[i][j]);
    }
  }
  #pragma unroll
  for (int i=0;i<4;i++){
    int j = j0 + ty*4 + i;
    float bias = bg[j];
    int bb = j >> 3, u = j & 7;
    #pragma unroll
    for (int jj=0;jj<4;jj++){
      int t = t0 + tx*4 + jj;
      size_t idx = ((size_t)bb*SEQ + t)*32 + u*4 + slot;
      _Float16 hv = (_Float16)(acc[i][jj] + bias);
      xp16[idx] = __builtin_bit_cast(unsigned short, hv);
    }
  }
}

// ---------------- Phase B: persistent scan — wave-autonomous units, direct global poll ----------------
// 256 blocks x 512 thr (8 waves). Wave w owns unit u = 8b+w (all 4 gate rows), f16 weights
// in 64 VGPR/lane. Consumers poll comm row t-1 DIRECTLY (8 B granules, lanes decoupled, no
// staging barrier). Producers gather 8 unit-h in LDS (parity dbuf), one barrier, wave 0
// publishes as two 8 B agent stores (each consumer granule = exactly one store; no tearing).
__global__ __launch_bounds__(512, 2)
void lstm_scan(const float* __restrict__ Wf, const float* __restrict__ Wi,
               const float* __restrict__ Wc, const float* __restrict__ Wo,
               const unsigned short* __restrict__ xp16,
               float* __restrict__ hist,            // d_out hidden region [SEQ][HID] fp32
               unsigned short* __restrict__ comm,   // [SEQ][HID] f16 exchange buffer
               const unsigned short* __restrict__ zcomm)  // 2048 f16 zeros (h_{-1})
{
  const int b    = blockIdx.x;
  const int tid  = threadIdx.x;
  const int w    = tid >> 6;
  const int lane = tid & 63;

  __shared__ unsigned short gh16[2][8] __attribute__((aligned(8)));  // f16 h gather
  __shared__ float          ghf [2][8];                              // fp32 h gather

  // f16 weights: w2[r][kc*4+m] covers cols 8*lane + 512*kc + 2m..2m+1 of gate-row r
  const float* rows[4] = { Wf + (size_t)(b*8+w)*3072, Wi + (size_t)(b*8+w)*3072,
                           Wc + (size_t)(b*8+w)*3072, Wo + (size_t)(b*8+w)*3072 };
  half2_t w2[4][16];
  #pragma unroll
  for (int r=0;r<4;r++){
    #pragma unroll
    for (int kc=0;kc<4;kc++){
      float4 f0 = *(const float4*)(rows[r] + 8*lane + 512*kc);
      float4 f1 = *(const float4*)(rows[r] + 8*lane + 512*kc + 4);
      w2[r][kc*4+0] = (half2_t){(_Float16)f0.x, (_Float16)f0.y};
      w2[r][kc*4+1] = (half2_t){(_Float16)f0.z, (_Float16)f0.w};
      w2[r][kc*4+2] = (half2_t){(_Float16)f1.x, (_Float16)f1.y};
      w2[r][kc*4+3] = (half2_t){(_Float16)f1.z, (_Float16)f1.w};
    }
  }

  float c = 0.0f;                                       // replicated across lanes
  const unsigned short* xpp = xp16 + (size_t)b*SEQ*32 + w*4 + lane;  // lane<4

  for (int t=0; t<SEQ; t++){
    // x-projection early (tiny, cached)
    float xp = 0.0f;
    if (lane < 4){
      _Float16 hv = __builtin_bit_cast(_Float16, xpp[(size_t)t*32]);
      xp = (float)hv;
    }

    // ---- issue all 8 granule loads up-front (overlapped), then fix up late ones ----
    const unsigned short* base = (t==0) ? zcomm : (comm + (size_t)(t-1)*HID);
    ull_t q[8];
    #pragma unroll
    for (int g2=0; g2<8; g2++){
      const ull_t* gp = (const ull_t*)(base + 8*lane + 512*(g2>>1) + 4*(g2&1));
      q[g2] = __hip_atomic_load(gp, __ATOMIC_RELAXED, __HIP_MEMORY_SCOPE_AGENT);
    }

    float a0=0.f, a1=0.f, a2=0.f, a3=0.f;   // gate rows f,i,c,o
    #pragma unroll
    for (int g2=0; g2<8; g2++){
      const ull_t* gp = (const ull_t*)(base + 8*lane + 512*(g2>>1) + 4*(g2&1));
      ull_t v = q[g2];
      int gd = 0;
      while (bad16(v) && ++gd < (1<<17))   // guard: fail wrong, never hang
        v = __hip_atomic_load(gp, __ATOMIC_RELAXED, __HIP_MEMORY_SCOPE_AGENT);
      half2_t h0 = u2h((unsigned)v), h1 = u2h((unsigned)(v>>32));
      const int kc = g2>>1, m = (g2&1)*2;
      a0=FDOT2(w2[0][kc*4+m],h0,a0); a0=FDOT2(w2[0][kc*4+m+1],h1,a0);
      a1=FDOT2(w2[1][kc*4+m],h0,a1); a1=FDOT2(w2[1][kc*4+m+1],h1,a1);
      a2=FDOT2(w2[2][kc*4+m],h0,a2); a2=FDOT2(w2[2][kc*4+m+1],h1,a2);
      a3=FDOT2(w2[3][kc*4+m],h0,a3); a3=FDOT2(w2[3][kc*4+m+1],h1,a3);
    }

    // ---- 7-shuffle multi-reduce: lane&3 -> 0:f 1:cbar 2:i 3:o (full 64-lane sums) ----
    bool s0sel = lane & 1;
    float s0 = s0sel ? a0 : a2;
    float s1 = s0sel ? a1 : a3;
    float k0 = s0sel ? a2 : a0;
    float k1 = s0sel ? a3 : a1;
    k0 += __shfl_xor(s0, 1);
    k1 += __shfl_xor(s1, 1);
    bool s1sel = lane & 2;
    float s2 = s1sel ? k0 : k1;
    float k2 = s1sel ? k1 : k0;
    k2 += __shfl_xor(s2, 2);
    k2 += __shfl_xor(k2, 4);
    k2 += __shfl_xor(k2, 8);
    k2 += __shfl_xor(k2, 16);
    k2 += __shfl_xor(k2, 32);

    float pre = k2 + xp;
    float act = ((lane & 3) == 1) ? tanh_f(pre) : sigmoid_f(pre);

    float f_g  = __shfl(act, 0);
    float cb_g = __shfl(act, 1);
    float i_g  = __shfl(act, 2);
    float o_g  = __shfl(act, 3);

    c = fmaf(f_g, c, i_g * cb_g);
    float h = o_g * tanh_f(c);

    // ---- gather in LDS (parity dbuf), one barrier, coalesced publish by wave 0 ----
    const int p = t & 1;
    if (lane == 0){
      _Float16 hv = (_Float16)h;
      gh16[p][w] = __builtin_bit_cast(unsigned short, hv);
      ghf [p][w] = h;
    }
    __syncthreads();                      // the ONLY barrier per step

    if (w == 0){
      if (lane == 0){
        ull_t lo = *(const ull_t*)&gh16[p][0];
        ull_t hi = *(const ull_t*)&gh16[p][4];
        ull_t* dst = (ull_t*)(comm + (size_t)t*HID + b*8);
        __hip_atomic_store(dst,   lo, __ATOMIC_RELAXED, __HIP_MEMORY_SCOPE_AGENT);
        __hip_atomic_store(dst+1, hi, __ATOMIC_RELAXED, __HIP_MEMORY_SCOPE_AGENT);
      }
      if (lane < 8)
        hist[(size_t)t*HID + b*8 + lane] = ghf[p][lane];   // fp32 out, off critical path
    }
  }
}

// ---------------- Phase C: y[t][o] = W_y[o] @ h_t + b_y[o] ----------------
__global__ __launch_bounds__(256)
void ygemm(const float* __restrict__ hist, const float* __restrict__ Wy,
           const float* __restrict__ by, float* __restrict__ yout)
{
  __shared__ float As[16][68];
  __shared__ float Bs[16][68];
  const int o0 = blockIdx.x * 64;
  const int t0 = blockIdx.y * 64;
  const int tid = threadIdx.x;
  const int tx = tid & 15, ty = tid >> 4;
  const int lr = tid >> 2;
  const int lk = (tid & 3) * 4;
  float acc[4][4] = {};
  for (int k0 = 0; k0 < HID; k0 += 16){
    float4 av = *(const float4*)(hist + (size_t)(t0+lr)*HID + k0 + lk);
    float4 bv = *(const float4*)(Wy   + (size_t)(o0+lr)*HID + k0 + lk);
    __syncthreads();
    As[lk+0][lr]=av.x; As[lk+1][lr]=av.y; As[lk+2][lr]=av.z; As[lk+3][lr]=av.w;
    Bs[lk+0][lr]=bv.x; Bs[lk+1][lr]=bv.y; Bs[lk+2][lr]=bv.z; Bs[lk+3][lr]=bv.w;
    __syncthreads();
    #pragma unroll
    for (int kk=0;kk<16;kk++){
      float a[4], bb[4];
      #pragma unroll
      for (int i=0;i<4;i++) a[i]  = As[kk][ty*4+i];
      #pragma unroll
      for (int j=0;j<4;j++) bb[j] = Bs[kk][tx*4+j];
      #pragma unroll
      for (int i=0;i<4;i++)
        #pragma unroll
        for (int j=0;j<4;j++)
          acc[i][j] = fmaf(a[i], bb[j], acc[i][j]);
    }
  }
  #pragma unroll
  for (int i=0;i<4;i++){
    int t = t0 + ty*4 + i;
    #pragma unroll
    for (int jj=0;jj<4;jj++){
      int o = o0 + tx*4 + jj;
      yout[(size_t)t*OUTW + o] = acc[i][jj] + by[o];
    }
  }
}

extern "C" void kernel_launch(void* const* d_in, const int* in_sizes, int n_in,
                              void* d_out, int out_size, void* d_ws, size_t ws_size,
                              hipStream_t stream) {
  const float* X  = (const float*)d_in[0];
  const float* Wf = (const float*)d_in[1];
  const float* bf = (const float*)d_in[2];
  const float* Wi = (const float*)d_in[3];
  const float* bi = (const float*)d_in[4];
  const float* Wc = (const float*)d_in[5];
  const float* bc = (const float*)d_in[6];
  const float* Wo = (const float*)d_in[7];
  const float* bo = (const float*)d_in[8];
  const float* Wy = (const float*)d_in[9];
  const float* by = (const float*)d_in[10];

  float* yout = (float*)d_out;                       // [2048][512]
  float* hist = (float*)d_out + (size_t)SEQ*OUTW;    // [2048][2048]

  const size_t XP_BYTES   = (size_t)256*SEQ*32*sizeof(unsigned short); // 16,777,216
  const size_t COMM_OFF   = XP_BYTES;
  const size_t COMM_BYTES = (size_t)SEQ*HID*sizeof(unsigned short);    //  8,388,608
  const size_t ZC_OFF     = COMM_OFF + COMM_BYTES;
  const size_t NEEDED     = ZC_OFF + HID*sizeof(unsigned short);
  if (ws_size < NEEDED) return;   // clean failure instead of corruption

  unsigned short* xp16  = (unsigned short*)d_ws;
  unsigned short* comm  = (unsigned short*)((char*)d_ws + COMM_OFF);
  unsigned short* zcomm = (unsigned short*)((char*)d_ws + ZC_OFF);

  fill_comm<<<(COMM_BYTES/16)/256, 256, 0, stream>>>((uint4*)comm, (uint4*)zcomm);

  dim3 gA(32, 128);
  xproj_gemm<<<gA, 256, 0, stream>>>(Wf,Wi,Wc,Wo, bf,bi,bc,bo, X, xp16);
  lstm_scan<<<256, 512, 0, stream>>>(Wf,Wi,Wc,Wo, xp16, hist, comm, zcomm);
  dim3 gY(8, 32);
  ygemm<<<gY, 256, 0, stream>>>(hist, Wy, by, yout);
}

// Round 5
// 6525.380 us; speedup vs baseline: 1.6254x; 1.6254x over previous
//
#include <hip/hip_runtime.h>
#include <stdint.h>

#define SEQ  2048
#define HID  2048
#define INP  1024
#define OUTW 512

typedef _Float16 half2_t __attribute__((ext_vector_type(2)));
typedef unsigned long long ull_t;

#if __has_builtin(__builtin_amdgcn_fdot2)
#define FDOT2(a,b,c) __builtin_amdgcn_fdot2((a),(b),(c),false)
#else
__device__ __forceinline__ float FDOT2(half2_t a, half2_t b, float c){
  return c + (float)a[0]*(float)b[0] + (float)a[1]*(float)b[1];
}
#endif

__device__ __forceinline__ half2_t u2h(unsigned int u){ return __builtin_bit_cast(half2_t, u); }
__device__ __forceinline__ float sigmoid_f(float x){ return 1.0f/(1.0f + __expf(-x)); }
__device__ __forceinline__ float tanh_f(float x){
  x = fminf(15.0f, fmaxf(-15.0f, x));
  float e = __expf(-2.0f*x);
  return (1.0f - e)/(1.0f + e);
}
// any 16-bit half still equal to the 0xFFFF sentinel? (real f16 h, |h|<1, never is)
__device__ __forceinline__ bool bad16(ull_t q){
  return ((unsigned short)(q)      == 0xFFFFu) | ((unsigned short)(q>>16) == 0xFFFFu) |
         ((unsigned short)(q>>32)  == 0xFFFFu) | ((unsigned short)(q>>48) == 0xFFFFu);
}

// ---------------- Phase 0: sentinel-fill comm (f16) + zero zcomm row ----------------
__global__ __launch_bounds__(256)
void fill_comm(uint4* __restrict__ comm4, uint4* __restrict__ zc4){
  size_t i = (size_t)blockIdx.x*256 + threadIdx.x;   // 524,288 uint4 = 8 MB
  comm4[i] = make_uint4(~0u,~0u,~0u,~0u);
  if (i < 256) zc4[i] = make_uint4(0,0,0,0);         // 4 KB f16 zeros
}

// ---------------- Phase A: xp16[b][t][u*4+slot] = f16(W_g[j][2048:]@x_t + b_g[j]) ----------------
// slot order per unit: [f, cbar, i, o] to match the scan's reduce lane mapping.
__global__ __launch_bounds__(256)
void xproj_gemm(const float* __restrict__ Wf, const float* __restrict__ Wi,
                const float* __restrict__ Wc, const float* __restrict__ Wo,
                const float* __restrict__ bfv, const float* __restrict__ biv,
                const float* __restrict__ bcv, const float* __restrict__ bov,
                const float* __restrict__ X, unsigned short* __restrict__ xp16)
{
  __shared__ float As[16][68];
  __shared__ float Bs[16][68];
  const int t0 = blockIdx.x * 64;
  const int r0 = blockIdx.y * 64;
  const int gate = r0 >> 11;
  const int j0 = r0 & 2047;
  const float* Wg = gate==0?Wf:gate==1?Wi:gate==2?Wc:Wo;
  const float* bg = gate==0?bfv:gate==1?biv:gate==2?bcv:bov;
  const int slot = (gate==0)?0:(gate==1)?2:(gate==2)?1:3;
  const int tid = threadIdx.x;
  const int tx = tid & 15, ty = tid >> 4;
  const int lr = tid >> 2;
  const int lk = (tid & 3) * 4;
  float acc[4][4] = {};
  for (int k0 = 0; k0 < INP; k0 += 16){
    float4 av = *(const float4*)(Wg + (size_t)(j0+lr)*3072 + 2048 + k0 + lk);
    float4 bv = *(const float4*)(X  + (size_t)(t0+lr)*INP  + k0 + lk);
    __syncthreads();
    As[lk+0][lr]=av.x; As[lk+1][lr]=av.y; As[lk+2][lr]=av.z; As[lk+3][lr]=av.w;
    Bs[lk+0][lr]=bv.x; Bs[lk+1][lr]=bv.y; Bs[lk+2][lr]=bv.z; Bs[lk+3][lr]=bv.w;
    __syncthreads();
    #pragma unroll
    for (int kk=0;kk<16;kk++){
      float a[4], bb[4];
      #pragma unroll
      for (int i=0;i<4;i++) a[i]  = As[kk][ty*4+i];
      #pragma unroll
      for (int j=0;j<4;j++) bb[j] = Bs[kk][tx*4+j];
      #pragma unroll
      for (int i=0;i<4;i++)
        #pragma unroll
        for (int j=0;j<4;j++)
          acc[i][j] = fmaf(a[i], bb[j], acc[i][j]);
    }
  }
  #pragma unroll
  for (int i=0;i<4;i++){
    int j = j0 + ty*4 + i;
    float bias = bg[j];
    int bb = j >> 3, u = j & 7;
    #pragma unroll
    for (int jj=0;jj<4;jj++){
      int t = t0 + tx*4 + jj;
      size_t idx = ((size_t)bb*SEQ + t)*32 + u*4 + slot;
      _Float16 hv = (_Float16)(acc[i][jj] + bias);
      xp16[idx] = __builtin_bit_cast(unsigned short, hv);
    }
  }
}

// ---------------- Phase B: persistent scan ----------------
// 256 blocks x 512 thr (8 waves). Wave w owns unit u = 8b+w (all 4 gate rows), f16
// weights in 64 VGPR/lane.
// Consumer (R3-proven): each thread polls ONE 8 B comm granule (coalesced, minimal
//   poll streams), stages to LDS parity buffer, barrier A.
// Producer (R4-proven): lane0/wave drops h into LDS, barrier B, wave 0 publishes the
//   block's 8 units as two 8 B agent stores — each consumer granule = one store, no
//   tearing — plus one coalesced 32 B fp32 hist store.
__global__ __launch_bounds__(512, 2)
void lstm_scan(const float* __restrict__ Wf, const float* __restrict__ Wi,
               const float* __restrict__ Wc, const float* __restrict__ Wo,
               const unsigned short* __restrict__ xp16,
               float* __restrict__ hist,            // d_out hidden region [SEQ][HID] fp32
               unsigned short* __restrict__ comm,   // [SEQ][HID] f16 exchange buffer
               const unsigned short* __restrict__ zcomm)  // 2048 f16 zeros (h_{-1})
{
  const int b    = blockIdx.x;
  const int tid  = threadIdx.x;
  const int w    = tid >> 6;
  const int lane = tid & 63;

  __shared__ unsigned int h16[2][1024];                              // f16 pairs, parity dbuf
  __shared__ unsigned short gh16[2][8] __attribute__((aligned(8)));  // f16 h gather
  __shared__ float          ghf [2][8];                              // fp32 h gather

  // f16 weights: w2[r][kc*4+m] covers cols 8*lane + 512*kc + 2m..2m+1 of gate-row r
  const float* rows[4] = { Wf + (size_t)(b*8+w)*3072, Wi + (size_t)(b*8+w)*3072,
                           Wc + (size_t)(b*8+w)*3072, Wo + (size_t)(b*8+w)*3072 };
  half2_t w2[4][16];
  #pragma unroll
  for (int r=0;r<4;r++){
    #pragma unroll
    for (int kc=0;kc<4;kc++){
      float4 f0 = *(const float4*)(rows[r] + 8*lane + 512*kc);
      float4 f1 = *(const float4*)(rows[r] + 8*lane + 512*kc + 4);
      w2[r][kc*4+0] = (half2_t){(_Float16)f0.x, (_Float16)f0.y};
      w2[r][kc*4+1] = (half2_t){(_Float16)f0.z, (_Float16)f0.w};
      w2[r][kc*4+2] = (half2_t){(_Float16)f1.x, (_Float16)f1.y};
      w2[r][kc*4+3] = (half2_t){(_Float16)f1.z, (_Float16)f1.w};
    }
  }

  float c = 0.0f;                                       // replicated across lanes
  const unsigned short* xpp = xp16 + (size_t)b*SEQ*32 + w*4 + lane;  // lane<4

  for (int t=0; t<SEQ; t++){
    // x-projection early (tiny, cached)
    float xp = 0.0f;
    if (lane < 4){
      _Float16 hv = __builtin_bit_cast(_Float16, xpp[(size_t)t*32]);
      xp = (float)hv;
    }

    // ---- acquire h_{t-1}: ONE 8 B granule per thread, coalesced sentinel poll ----
    const ull_t* hp = (t==0) ? ((const ull_t*)zcomm + tid)
                             : ((const ull_t*)(comm + (size_t)(t-1)*HID) + tid);
    ull_t q = __hip_atomic_load(hp, __ATOMIC_RELAXED, __HIP_MEMORY_SCOPE_AGENT);
    int gd = 0;
    while (bad16(q) && ++gd < (1<<17))   // guard: fail wrong, never hang
      q = __hip_atomic_load(hp, __ATOMIC_RELAXED, __HIP_MEMORY_SCOPE_AGENT);

    const int p = t & 1;
    *(uint2*)&h16[p][2*tid] = make_uint2((unsigned)q, (unsigned)(q>>32));
    __syncthreads();                     // barrier A

    // ---- dot: 4 gate rows x 32 cols/lane, f16 dot2 into fp32 ----
    float a0=0.f, a1=0.f, a2=0.f, a3=0.f;   // gate rows f,i,c,o
    #pragma unroll
    for (int kc=0;kc<4;kc++){
      uint4 hw = *(const uint4*)&h16[p][4*lane + 256*kc];
      half2_t h0=u2h(hw.x), h1=u2h(hw.y), h2=u2h(hw.z), h3=u2h(hw.w);
      a0=FDOT2(w2[0][kc*4+0],h0,a0); a0=FDOT2(w2[0][kc*4+1],h1,a0);
      a0=FDOT2(w2[0][kc*4+2],h2,a0); a0=FDOT2(w2[0][kc*4+3],h3,a0);
      a1=FDOT2(w2[1][kc*4+0],h0,a1); a1=FDOT2(w2[1][kc*4+1],h1,a1);
      a1=FDOT2(w2[1][kc*4+2],h2,a1); a1=FDOT2(w2[1][kc*4+3],h3,a1);
      a2=FDOT2(w2[2][kc*4+0],h0,a2); a2=FDOT2(w2[2][kc*4+1],h1,a2);
      a2=FDOT2(w2[2][kc*4+2],h2,a2); a2=FDOT2(w2[2][kc*4+3],h3,a2);
      a3=FDOT2(w2[3][kc*4+0],h0,a3); a3=FDOT2(w2[3][kc*4+1],h1,a3);
      a3=FDOT2(w2[3][kc*4+2],h2,a3); a3=FDOT2(w2[3][kc*4+3],h3,a3);
    }

    // ---- 7-shuffle multi-reduce: lane&3 -> 0:f 1:cbar 2:i 3:o (full 64-lane sums) ----
    bool s0sel = lane & 1;
    float s0 = s0sel ? a0 : a2;
    float s1 = s0sel ? a1 : a3;
    float k0 = s0sel ? a2 : a0;
    float k1 = s0sel ? a3 : a1;
    k0 += __shfl_xor(s0, 1);
    k1 += __shfl_xor(s1, 1);
    bool s1sel = lane & 2;
    float s2 = s1sel ? k0 : k1;
    float k2 = s1sel ? k1 : k0;
    k2 += __shfl_xor(s2, 2);
    k2 += __shfl_xor(k2, 4);
    k2 += __shfl_xor(k2, 8);
    k2 += __shfl_xor(k2, 16);
    k2 += __shfl_xor(k2, 32);

    float pre = k2 + xp;
    float act = ((lane & 3) == 1) ? tanh_f(pre) : sigmoid_f(pre);

    float f_g  = __shfl(act, 0);
    float cb_g = __shfl(act, 1);
    float i_g  = __shfl(act, 2);
    float o_g  = __shfl(act, 3);

    c = fmaf(f_g, c, i_g * cb_g);
    float h = o_g * tanh_f(c);

    // ---- gather in LDS, barrier B, single-transaction publish by wave 0 ----
    if (lane == 0){
      _Float16 hv = (_Float16)h;
      gh16[p][w] = __builtin_bit_cast(unsigned short, hv);
      ghf [p][w] = h;
    }
    __syncthreads();                      // barrier B

    if (w == 0){
      if (lane == 0){
        ull_t lo = *(const ull_t*)&gh16[p][0];
        ull_t hi = *(const ull_t*)&gh16[p][4];
        ull_t* dst = (ull_t*)(comm + (size_t)t*HID + b*8);
        __hip_atomic_store(dst,   lo, __ATOMIC_RELAXED, __HIP_MEMORY_SCOPE_AGENT);
        __hip_atomic_store(dst+1, hi, __ATOMIC_RELAXED, __HIP_MEMORY_SCOPE_AGENT);
      }
      if (lane < 8)
        hist[(size_t)t*HID + b*8 + lane] = ghf[p][lane];   // fp32 out, off critical path
    }
  }
}

// ---------------- Phase C: y[t][o] = W_y[o] @ h_t + b_y[o] ----------------
__global__ __launch_bounds__(256)
void ygemm(const float* __restrict__ hist, const float* __restrict__ Wy,
           const float* __restrict__ by, float* __restrict__ yout)
{
  __shared__ float As[16][68];
  __shared__ float Bs[16][68];
  const int o0 = blockIdx.x * 64;
  const int t0 = blockIdx.y * 64;
  const int tid = threadIdx.x;
  const int tx = tid & 15, ty = tid >> 4;
  const int lr = tid >> 2;
  const int lk = (tid & 3) * 4;
  float acc[4][4] = {};
  for (int k0 = 0; k0 < HID; k0 += 16){
    float4 av = *(const float4*)(hist + (size_t)(t0+lr)*HID + k0 + lk);
    float4 bv = *(const float4*)(Wy   + (size_t)(o0+lr)*HID + k0 + lk);
    __syncthreads();
    As[lk+0][lr]=av.x; As[lk+1][lr]=av.y; As[lk+2][lr]=av.z; As[lk+3][lr]=av.w;
    Bs[lk+0][lr]=bv.x; Bs[lk+1][lr]=bv.y; Bs[lk+2][lr]=bv.z; Bs[lk+3][lr]=bv.w;
    __syncthreads();
    #pragma unroll
    for (int kk=0;kk<16;kk++){
      float a[4], bb[4];
      #pragma unroll
      for (int i=0;i<4;i++) a[i]  = As[kk][ty*4+i];
      #pragma unroll
      for (int j=0;j<4;j++) bb[j] = Bs[kk][tx*4+j];
      #pragma unroll
      for (int i=0;i<4;i++)
        #pragma unroll
        for (int j=0;j<4;j++)
          acc[i][j] = fmaf(a[i], bb[j], acc[i][j]);
    }
  }
  #pragma unroll
  for (int i=0;i<4;i++){
    int t = t0 + ty*4 + i;
    #pragma unroll
    for (int jj=0;jj<4;jj++){
      int o = o0 + tx*4 + jj;
      yout[(size_t)t*OUTW + o] = acc[i][jj] + by[o];
    }
  }
}

extern "C" void kernel_launch(void* const* d_in, const int* in_sizes, int n_in,
                              void* d_out, int out_size, void* d_ws, size_t ws_size,
                              hipStream_t stream) {
  const float* X  = (const float*)d_in[0];
  const float* Wf = (const float*)d_in[1];
  const float* bf = (const float*)d_in[2];
  const float* Wi = (const float*)d_in[3];
  const float* bi = (const float*)d_in[4];
  const float* Wc = (const float*)d_in[5];
  const float* bc = (const float*)d_in[6];
  const float* Wo = (const float*)d_in[7];
  const float* bo = (const float*)d_in[8];
  const float* Wy = (const float*)d_in[9];
  const float* by = (const float*)d_in[10];

  float* yout = (float*)d_out;                       // [2048][512]
  float* hist = (float*)d_out + (size_t)SEQ*OUTW;    // [2048][2048]

  const size_t XP_BYTES   = (size_t)256*SEQ*32*sizeof(unsigned short); // 16,777,216
  const size_t COMM_OFF   = XP_BYTES;
  const size_t COMM_BYTES = (size_t)SEQ*HID*sizeof(unsigned short);    //  8,388,608
  const size_t ZC_OFF     = COMM_OFF + COMM_BYTES;
  const size_t NEEDED     = ZC_OFF + HID*sizeof(unsigned short);
  if (ws_size < NEEDED) return;   // clean failure instead of corruption

  unsigned short* xp16  = (unsigned short*)d_ws;
  unsigned short* comm  = (unsigned short*)((char*)d_ws + COMM_OFF);
  unsigned short* zcomm = (unsigned short*)((char*)d_ws + ZC_OFF);

  fill_comm<<<(COMM_BYTES/16)/256, 256, 0, stream>>>((uint4*)comm, (uint4*)zcomm);

  dim3 gA(32, 128);
  xproj_gemm<<<gA, 256, 0, stream>>>(Wf,Wi,Wc,Wo, bf,bi,bc,bo, X, xp16);
  lstm_scan<<<256, 512, 0, stream>>>(Wf,Wi,Wc,Wo, xp16, hist, comm, zcomm);
  dim3 gY(8, 32);
  ygemm<<<gY, 256, 0, stream>>>(hist, Wy, by, yout);
}